// Round 6
// baseline (1903.309 us; speedup 1.0000x reference)
//
#include <hip/hip_runtime.h>
#include <hip/hip_bf16.h>

// RNN: B=4096, T=1024, H=40, K=41. fp32 compute & state (dtype autodetected).
// Round-16: union row-slots -- residency-feasible AND issue-lean.
// R15 post-mortem: pk_fma halving converted ~1:1 to wall time (877->743,
// VALUBusy 77->48) => ISSUE VOLUME IS KING. Remaining taxes: (1) remat
// (demand ~215 floats vs VGPR 112 -> ~100 floats reloaded from global per
// thread-step, serial-chain vmcnt waits); (2) only 2 waves/SIMD (22% occ).
// R10-R15 conflict: residency wants few rows/lane; state-read amortization
// wants many. Resolution: UNION slots.
//   256 thr/block (4 waves), el = tid&3, worker w = tid>>2 (0..63), 4 els.
//   slot0 (all lanes):   A-row j=w      (L1: rows 0..63)
//   slot1 (wave 0):      A-row j=64+w   (L1: rows 64..79, h2o rows 24..39)
//   slot1 (waves 1-3, w<=56): B-row r=w-16 (L2 rows 0..39; w==56 -> OUTPUT)
//   -> 80 weight floats + 6 scalars + ~8 window + ~8 acc + misc ~= 125 <= 128.
//   First structure where residency is feasible AND rows/lane ~= 2.
//   Grid 1024 x 4 waves = 16 waves/CU = 4 waves/SIMD (2x TLP vs R15).
//   __launch_bounds__(256,4): VGPR cap exactly 128.
//   Output row unified with L2 dot via per-lane base pointer (&sA[el][40]
//   vs &sA[el][0]) -- single code path, no extra divergence.
// Coverage: A rows 0..79 exactly once (w: 0..63; wave0 slot1: 64..79);
// B rows 0..39 exactly once (w=16..55), output w=56; w=57..63 B-idle.
// Bank math mod 32: sA stride 84==20: writes el*20+w (16-wide ranges/wave)
// <=2-way; sH stride 44==12: writes el*12+r <=3-way (1 instr, negligible);
// reads: 16 same-el lanes share address -> 4 distinct 16B/instr (R15 pattern).
// 2 barriers/step. Dual-template dtype safety (proven rounds 3-15).

#define B_SZ 4096
#define T_SZ 1024
#define HID  40

typedef unsigned short u16;
typedef unsigned int   u32;
typedef float f2 __attribute__((ext_vector_type(2)));

__device__ __forceinline__ float bf2f(u16 v) {
  union { u32 u; float f; } c; c.u = ((u32)v) << 16; return c.f;
}

template <bool BF>
__device__ __forceinline__ float ldg(const void* p, long i) {
  if (BF) return bf2f(((const u16*)p)[i]);
  return ((const float*)p)[i];
}

template <bool BF>
__device__ __forceinline__ f2 ldg2(const void* p, long i) {
  f2 r;
  r.x = ldg<BF>(p, i + 0);
  r.y = ldg<BF>(p, i + 1);
  return r;
}

// Proven rounds 3-15: true-bf16 weights all have |w| <= 1/sqrt(41) ~ 0.156;
// fp32 data read as bf16 halfwords exceeds 0.2 with P ~ 1-1e-10.
__device__ __forceinline__ bool detect_bf16(const void* w) {
  const u16* p = (const u16*)w;
  bool bf = true;
  for (int i = 0; i < 64; ++i) {
    float f = bf2f(p[i]);
    if (!(fabsf(f) <= 0.2f)) bf = false;
  }
  return bf;
}

template <bool BF>
__global__ __launch_bounds__(256, 4)
void rnn_kernel(const void* __restrict__ inp,
                const void* __restrict__ h2h_w1, const void* __restrict__ h2h_b1,
                const void* __restrict__ h2h_w2, const void* __restrict__ h2h_b2,
                const void* __restrict__ h2o_w1, const void* __restrict__ h2o_b1,
                const void* __restrict__ h2o_w2, const void* __restrict__ h2o_b2,
                void* __restrict__ out) {
  __shared__ __align__(16) float sH[4][44];  // state   [el][k] (176 B stride)
  __shared__ __align__(16) float sA[4][84];  // l1 acts [el][j] (336 B stride)

  if (detect_bf16(h2h_w1) != BF) return;  // wrong-dtype instantiation exits

  const int tid = threadIdx.x;
  const int el  = tid & 3;          // batch element within block
  const int w   = tid >> 2;         // worker 0..63
  const int wv  = tid >> 6;         // wave 0..3 (wave-uniform)
  const bool two = (wv == 0);       // wave0: second A-row in slot1

  // ---- slot0: A-row j = w (all lanes) ----
  f2    wS0[20];
  float wu0, ba0;
  {
    const bool hh = (w < HID);
    const void* w1p = hh ? h2h_w1 : h2o_w1;
    const long  jr  = hh ? w : (w - HID);
    wu0 = ldg<BF>(w1p, jr * 41);
    ba0 = ldg<BF>(hh ? h2h_b1 : h2o_b1, jr);
#pragma unroll
    for (int i = 0; i < 20; ++i)
      wS0[i] = ldg2<BF>(w1p, jr * 41 + 1 + 2 * i);
  }

  // ---- slot1 (union): wave0 -> A-row 64+w; waves1-3 (w<=56) -> B-row ----
  f2    wS1[20];
  float wuX = 0.f, baX = 0.f, bbX = 0.f;
#pragma unroll
  for (int i = 0; i < 20; ++i) wS1[i] = (f2)0.f;
  if (two) {                        // h2o layer-1 row 24+w (global row 64+w)
    const long jr = 24 + w;
    wuX = ldg<BF>(h2o_w1, jr * 41);
    baX = ldg<BF>(h2o_b1, jr);
#pragma unroll
    for (int i = 0; i < 20; ++i)
      wS1[i] = ldg2<BF>(h2o_w1, jr * 41 + 1 + 2 * i);
  } else if (w <= 56) {             // L2 row w-16, or output row (w==56)
    const bool isout = (w == 56);
    const void* w2p = isout ? h2o_w2 : h2h_w2;
    const long  rr  = isout ? 0 : (w - 16);
    bbX = isout ? ldg<BF>(h2o_b2, 0) : ldg<BF>(h2h_b2, w - 16);
#pragma unroll
    for (int i = 0; i < 20; ++i)
      wS1[i] = ldg2<BF>(w2p, rr * 40 + 2 * i);
  }

  for (int i = tid; i < 4 * 44; i += 256) ((float*)sH)[i] = 0.f;
  __syncthreads();

  const int  b    = blockIdx.x * 4 + el;
  const long base = (long)b * T_SZ;
  float u_cur = ldg<BF>(inp, base);

  const f2* hp = (const f2*)sH[el];   // state (k-pairs), loop-invariant

  for (int t = 0; t < T_SZ; ++t) {
    const float u_nxt = (t + 1 < T_SZ) ? ldg<BF>(inp, base + t + 1) : 0.f;

    // ---------- Phase A: layer 1 (80 rows) ----------
    f2 ac00 = {0.f, 0.f}, ac01 = {0.f, 0.f};
    f2 ac10 = {0.f, 0.f}, ac11 = {0.f, 0.f};
#pragma unroll
    for (int m = 0; m < 5; ++m) {     // 8 k per window (2 b128 reads)
      const f2 h0 = hp[4 * m + 0], h1 = hp[4 * m + 1];
      const f2 h2 = hp[4 * m + 2], h3 = hp[4 * m + 3];
      ac00 = h0 * wS0[4 * m + 0] + ac00;
      ac00 = h1 * wS0[4 * m + 1] + ac00;
      ac01 = h2 * wS0[4 * m + 2] + ac01;
      ac01 = h3 * wS0[4 * m + 3] + ac01;
      if (two) {                      // wave-uniform branch
        ac10 = h0 * wS1[4 * m + 0] + ac10;
        ac10 = h1 * wS1[4 * m + 1] + ac10;
        ac11 = h2 * wS1[4 * m + 2] + ac11;
        ac11 = h3 * wS1[4 * m + 3] + ac11;
      }
    }
    {
      const float a0 = fmaf(u_cur, wu0, ba0) + ac00.x + ac00.y + ac01.x + ac01.y;
      sA[el][w] = fmaxf(a0, 0.01f * a0);          // LeakyReLU(0.01)
    }
    if (two) {
      const float a1 = fmaf(u_cur, wuX, baX) + ac10.x + ac10.y + ac11.x + ac11.y;
      sA[el][64 + w] = fmaxf(a1, 0.01f * a1);
    }
    __syncthreads();   // sA visible; all sH reads done

    // ---------- Phase B: layer 2 (40 hidden rows + output) ----------
    if (!two && w <= 56) {
      // unified base: L2 rows read a-acts [0..39]; output reads o-acts [40..79]
      const f2* ap = (const f2*)(&sA[el][(w == 56) ? 40 : 0]);
      f2 bc0 = {0.f, 0.f}, bc1 = {0.f, 0.f};
#pragma unroll
      for (int m = 0; m < 5; ++m) {
        const f2 a0 = ap[4 * m + 0], a1 = ap[4 * m + 1];
        const f2 a2 = ap[4 * m + 2], a3 = ap[4 * m + 3];
        bc0 = a0 * wS1[4 * m + 0] + bc0;
        bc0 = a1 * wS1[4 * m + 1] + bc0;
        bc1 = a2 * wS1[4 * m + 2] + bc1;
        bc1 = a3 * wS1[4 * m + 3] + bc1;
      }
      const float v = bbX + bc0.x + bc0.y + bc1.x + bc1.y;
      if (w < 56) {
        sH[el][w - 16] = v;
      } else {
        if (BF) ((__hip_bfloat16*)out)[base + t] = __float2bfloat16(v);
        else    ((float*)out)[base + t] = v;
      }
    }
    __syncthreads();   // sH update + sA reads done before next step

    u_cur = u_nxt;
  }
}

extern "C" void kernel_launch(void* const* d_in, const int* in_sizes, int n_in,
                              void* d_out, int out_size, void* d_ws, size_t ws_size,
                              hipStream_t stream) {
  (void)in_sizes; (void)n_in; (void)out_size; (void)d_ws; (void)ws_size;
  rnn_kernel<false><<<dim3(B_SZ / 4), dim3(256), 0, stream>>>(
      d_in[0], d_in[1], d_in[2], d_in[3], d_in[4],
      d_in[5], d_in[6], d_in[7], d_in[8], d_out);
  rnn_kernel<true><<<dim3(B_SZ / 4), dim3(256), 0, stream>>>(
      d_in[0], d_in[1], d_in[2], d_in[3], d_in[4],
      d_in[5], d_in[6], d_in[7], d_in[8], d_out);
}

// Round 7
// 1335.240 us; speedup vs baseline: 1.4254x; 1.4254x over previous
//
#include <hip/hip_runtime.h>
#include <hip/hip_bf16.h>

// RNN: B=4096, T=1024, H=40, K=41. fp32 compute & state (dtype autodetected).
// Round-17: 128 lanes per element -- weights/lane = 4961/128 ~ 44 floats.
// R16 post-mortem: WRITE_SIZE 16MB->240MB + VGPR 64 = scratch spill in-loop
// (union slot not remat-able). Allocator model complete: it allocates 64-112
// VGPRs regardless of attributes; excess demand is remat'd (if clean loads)
// or spilled (if not). Also: resident waves = els * lanes_per_el / 64; at
// 16 lanes/el occupancy is pinned to 2 waves/SIMD forever. lanes_per_el=128
// fixes BOTH: demand 44 fits any allocator choice; 8192 waves = 4-5/SIMD.
// Structure (128 thr = 2 waves, 1 el/block, grid 4096):
//   pair p = tid>>1 (0..63), kh = tid&1 (K-half), DPP lane^1 pair-reduce
//   (proven R11-R16). All phases issue-uniform across the full wave; only
//   writes are masked.
//   Phase 1: pair p <-> L1 row p (p<40: h2h-L1 -> sA[p]; 40..63: h2o-L1 ->
//            sO[cb][p-40]).  kh0: u*wu + b + h[0..19]; kh1: h[20..39].
//   Phase 2 (ONE body, per-lane ptr select):
//     p<40  : L2 hidden row p: reads sA, writes sH[nb][p]
//     40..55: L1 rows 64..79 : reads sH[cb], writes sO[cb][24+(p-40)]
//     p==56 : OUTPUT row, LAGGED: reads sO[(t-1)&1] (prev step, complete),
//             stores y(t-1); tail after loop emits y(T-1). y does not feed
//             the recurrence -> lag is exact, not approximate.
//     p>56  : computes garbage (uniform issue), writes nothing.
//   sH,sO double-buffered -> no intra-phase races; sA produced ph1/consumed
//   ph2 same step. 2 barriers/step. LDS ~816B.
// Per-thread live: 44 weights + 20 state-slice + ~15 scratch ~= 80 -> fits
// even a 96-VGPR allocation with zero remat/spill.
// Numerics: same kh-split sum order as R11-R16 (absmax-proven).

#define B_SZ 4096
#define T_SZ 1024
#define HID  40

typedef unsigned short u16;
typedef unsigned int   u32;
typedef float f2 __attribute__((ext_vector_type(2)));

__device__ __forceinline__ float bf2f(u16 v) {
  union { u32 u; float f; } c; c.u = ((u32)v) << 16; return c.f;
}

template <bool BF>
__device__ __forceinline__ float ldg(const void* p, long i) {
  if (BF) return bf2f(((const u16*)p)[i]);
  return ((const float*)p)[i];
}

template <bool BF>
__device__ __forceinline__ f2 ldg2(const void* p, long i) {
  f2 r;
  r.x = ldg<BF>(p, i + 0);
  r.y = ldg<BF>(p, i + 1);
  return r;
}

// Proven rounds 3-16: true-bf16 weights all have |w| <= 1/sqrt(41) ~ 0.156;
// fp32 data read as bf16 halfwords exceeds 0.2 with P ~ 1-1e-10.
__device__ __forceinline__ bool detect_bf16(const void* w) {
  const u16* p = (const u16*)w;
  bool bf = true;
  for (int i = 0; i < 64; ++i) {
    float f = bf2f(p[i]);
    if (!(fabsf(f) <= 0.2f)) bf = false;
  }
  return bf;
}

// Partner value from lane^1 (quad_perm [1,0,3,2]). VALU pipe, no LDS.
__device__ __forceinline__ float pair_other(float x) {
  return __int_as_float(__builtin_amdgcn_update_dpp(
      0, __float_as_int(x), 0xB1, 0xF, 0xF, true));
}

template <bool BF>
__global__ __launch_bounds__(128, 2)
void rnn_kernel(const void* __restrict__ inp,
                const void* __restrict__ h2h_w1, const void* __restrict__ h2h_b1,
                const void* __restrict__ h2h_w2, const void* __restrict__ h2h_b2,
                const void* __restrict__ h2o_w1, const void* __restrict__ h2o_b1,
                const void* __restrict__ h2o_w2, const void* __restrict__ h2o_b2,
                void* __restrict__ out) {
  __shared__ __align__(16) float sH[2][40];  // state double-buffer
  __shared__ __align__(16) float sA[44];     // a-acts (L1 rows 0..39)
  __shared__ __align__(16) float sO[2][40];  // o-acts double-buffer (rows 40..79)

  if (detect_bf16(h2h_w1) != BF) return;  // wrong-dtype instantiation exits

  const int tid  = threadIdx.x;     // 0..127
  const int kh   = tid & 1;         // K-half: 0 -> k 0..19 (+u), 1 -> k 20..39
  const int p    = tid >> 1;        // pair 0..63
  const int koff = kh * 20;

  // ---- Phase-1 weights: L1 row j = p (20 floats + u-weight + bias) ----
  f2    w1s[10];
  float wu1, ba1;
  {
    const bool hh = (p < HID);
    const void* wp = hh ? h2h_w1 : h2o_w1;
    const long  jr = hh ? p : (p - HID);
    wu1 = (kh == 0) ? ldg<BF>(wp, jr * 41) : 0.f;
    ba1 = (kh == 0) ? ldg<BF>(hh ? h2h_b1 : h2o_b1, jr) : 0.f;
#pragma unroll
    for (int i = 0; i < 10; ++i)
      w1s[i] = ldg2<BF>(wp, jr * 41 + 1 + koff + 2 * i);
  }

  // ---- Phase-2 weights (20 floats + optional u-weight + bias) ----
  f2    w2s[10];
  float wu2 = 0.f, bb2 = 0.f;
#pragma unroll
  for (int i = 0; i < 10; ++i) w2s[i] = (f2)0.f;
  if (p < HID) {                       // L2 hidden row p
    if (kh == 0) bb2 = ldg<BF>(h2h_b2, p);
#pragma unroll
    for (int i = 0; i < 10; ++i)
      w2s[i] = ldg2<BF>(h2h_w2, (long)p * HID + koff + 2 * i);
  } else if (p < 56) {                 // L1 row 64+(p-40) = h2o-L1 row 24+(p-40)
    const long jr = 24 + (p - 40);
    if (kh == 0) { wu2 = ldg<BF>(h2o_w1, jr * 41); bb2 = ldg<BF>(h2o_b1, jr); }
#pragma unroll
    for (int i = 0; i < 10; ++i)
      w2s[i] = ldg2<BF>(h2o_w1, jr * 41 + 1 + koff + 2 * i);
  } else if (p == 56) {                // output row (lagged)
    if (kh == 0) bb2 = ldg<BF>(h2o_b2, 0);
#pragma unroll
    for (int i = 0; i < 10; ++i)
      w2s[i] = ldg2<BF>(h2o_w2, koff + 2 * i);
  }

  // Zero state + both o-act buffers (t=0 reads sH[0]; t=0 p56 reads sO[1])
  for (int i = tid; i < 80; i += 128) { ((float*)sH)[i] = 0.f; ((float*)sO)[i] = 0.f; }
  if (tid < 44) sA[tid] = 0.f;
  __syncthreads();

  const long base = (long)blockIdx.x * T_SZ;   // 1 el per block
  float u_cur = ldg<BF>(inp, base);

  // Parity-selected pointers (computed once; per-step select = 1 cndmask)
  const f2* h_rd0 = (const f2*)(&sH[0][koff]);
  const f2* h_rd1 = (const f2*)(&sH[1][koff]);
  float* w1p0 = (p < HID) ? &sA[p] : &sO[0][p - HID];
  float* w1p1 = (p < HID) ? &sA[p] : &sO[1][p - HID];
  const f2* r20 = (p < HID)  ? (const f2*)(&sA[koff])
                : (p < 56)   ? (const f2*)(&sH[0][koff])
                : (p == 56)  ? (const f2*)(&sO[1][koff])
                             : (const f2*)(&sA[koff]);
  const f2* r21 = (p < HID)  ? (const f2*)(&sA[koff])
                : (p < 56)   ? (const f2*)(&sH[1][koff])
                : (p == 56)  ? (const f2*)(&sO[0][koff])
                             : (const f2*)(&sA[koff]);
  float* w2p0 = (p < HID) ? &sH[1][p] : (p < 56 ? &sO[0][24 + (p - 40)] : &sA[40]);
  float* w2p1 = (p < HID) ? &sH[0][p] : (p < 56 ? &sO[1][24 + (p - 40)] : &sA[40]);
  const bool leaky2 = (p >= HID) && (p < 56);
  const bool wr2    = (kh == 0) && (p < 56);
  const bool wrY    = (kh == 0) && (p == 56);

  for (int t = 0; t < T_SZ; ++t) {
    const bool odd = (t & 1);
    const float u_nxt = (t + 1 < T_SZ) ? ldg<BF>(inp, base + t + 1) : 0.f;

    // ---------- Phase 1: L1 rows 0..63 (uniform) ----------
    {
      const f2* hp = odd ? h_rd1 : h_rd0;
      f2 hv[10];
#pragma unroll
      for (int i = 0; i < 10; ++i) hv[i] = hp[i];
      f2 acc = {0.f, 0.f};
#pragma unroll
      for (int i = 0; i < 10; ++i) acc = hv[i] * w1s[i] + acc;
      const float s1 = fmaf(u_cur, wu1, ba1) + acc.x + acc.y;
      const float t1 = s1 + pair_other(s1);          // combine K-halves
      const float a1 = fmaxf(t1, 0.01f * t1);        // LeakyReLU(0.01)
      if (kh == 0) *(odd ? w1p1 : w1p0) = a1;
    }
    __syncthreads();   // sA + sO[cb][0..23] visible; sH[cb] reads done

    // ---------- Phase 2: ONE body for L2 rows / L1 tail / output ----------
    {
      const f2* rp = odd ? r21 : r20;
      f2 av[10];
#pragma unroll
      for (int i = 0; i < 10; ++i) av[i] = rp[i];
      f2 acc = {0.f, 0.f};
#pragma unroll
      for (int i = 0; i < 10; ++i) acc = av[i] * w2s[i] + acc;
      const float s2 = fmaf(u_cur, wu2, bb2) + acc.x + acc.y;
      const float t2 = s2 + pair_other(s2);
      const float v2 = leaky2 ? fmaxf(t2, 0.01f * t2) : t2;
      if (wr2) *(odd ? w2p1 : w2p0) = v2;
      if (wrY && t > 0) {                            // y(t-1), lagged store
        if (BF) ((__hip_bfloat16*)out)[base + t - 1] = __float2bfloat16(v2);
        else    ((float*)out)[base + t - 1] = v2;
      }
    }
    __syncthreads();   // sH[nb] + sO[cb][24..39] ready; sA reads done

    u_cur = u_nxt;
  }

  // ---------- Tail: y(T-1) from sO[(T-1)&1] = sO[1] ----------
  if (p == 56) {
    const f2* rp = (const f2*)(&sO[1][koff]);
    f2 acc = {0.f, 0.f};
#pragma unroll
    for (int i = 0; i < 10; ++i) acc = rp[i] * w2s[i] + acc;
    const float s2 = bb2 + acc.x + acc.y;
    const float t2 = s2 + pair_other(s2);
    if (kh == 0) {
      if (BF) ((__hip_bfloat16*)out)[base + T_SZ - 1] = __float2bfloat16(t2);
      else    ((float*)out)[base + T_SZ - 1] = t2;
    }
  }
}

extern "C" void kernel_launch(void* const* d_in, const int* in_sizes, int n_in,
                              void* d_out, int out_size, void* d_ws, size_t ws_size,
                              hipStream_t stream) {
  (void)in_sizes; (void)n_in; (void)out_size; (void)d_ws; (void)ws_size;
  rnn_kernel<false><<<dim3(B_SZ), dim3(128), 0, stream>>>(
      d_in[0], d_in[1], d_in[2], d_in[3], d_in[4],
      d_in[5], d_in[6], d_in[7], d_in[8], d_out);
  rnn_kernel<true><<<dim3(B_SZ), dim3(128), 0, stream>>>(
      d_in[0], d_in[1], d_in[2], d_in[3], d_in[4],
      d_in[5], d_in[6], d_in[7], d_in[8], d_out);
}

// Round 8
// 816.162 us; speedup vs baseline: 2.3320x; 1.6360x over previous
//
#include <hip/hip_runtime.h>
#include <hip/hip_bf16.h>

// RNN: B=4096, T=1024, H=40, K=41. fp32 compute & state (dtype autodetected).
// Round-18: 1 wave = 1 element. Model from R10-R17:
//  - issue volume converts ~1:1 to time (R15 pk_fma win);
//  - allocator remats invariant loads regardless of attributes (alloc 40-112);
//    only structural demand ~<=120 avoids a big reload tax;
//  - els/CU fixed at 16; minimize per-step chain AND per-el issues together;
//  - R17 (2 waves/el) doubled per-el cost; R15 (2 els/wave) paid ~100
//    remat floats/lane-step (FETCH 8.3MB) and 2-wave lockstep.
// Structure: 64-thr single-wave blocks, grid 4096 (16 waves/CU = 4/SIMD).
//   kh = lane&1 (K-half, DPP lane^1 pair-reduce -- proven R11+),
//   w = lane>>1 (32 workers). Four 20-float weight slots (<=80 floats/lane):
//     slot0/1: L1 rows {2w, 2w+1}            (rows 0..63)
//     slot2  : w>=16 -> L1 row 48+w (64..79) | w<16 -> L2 row w (0..15)
//     slot3  : w<24 -> L2 row 16+w (16..39)  | w==24 -> OUTPUT row | idle
//   Loads via pre-selected pointer+offset (remat-friendly; R16's spill came
//   from the 256-thr block + branchy union, avoided here).
//   Single-wave block => __syncthreads degenerates to waitcnt (no cross-wave
//   lockstep); LDS ops within a wave are in-order => single-buffered sH/sA.
//   Phase A: slots 0,1,2 vs state (slot2 garbage for w<16, not written);
//            acts: sA[2w],sA[2w+1] (b64), w>=16: sA[48+w]. All 80 L1 acts.
//   Phase B: slots 2,3 vs a-acts (w24 reads o-acts base; broadcast 2-addr);
//            writes new h: w<16: sH[w] (slot2), w<24: sH[16+w] (slot3);
//            w24: y(t) global store. L2/output rows have NO leaky (ref).
//   LDS/wave-step: 10 b128 broadcast reads + ~4 writes (lowest of any round).
//   Bank math: reads broadcast (<=2 addrs); b64 act-writes 2-way (free,
//   m136); b32 writes distinct banks. ~0 conflicts.
// Numerics: kh-split + pk_fma pairwise sums (absmax-stable across R10-R17).

#define B_SZ 4096
#define T_SZ 1024
#define HID  40

typedef unsigned short u16;
typedef unsigned int   u32;
typedef float f2 __attribute__((ext_vector_type(2)));
typedef float f4 __attribute__((ext_vector_type(4)));

__device__ __forceinline__ float bf2f(u16 v) {
  union { u32 u; float f; } c; c.u = ((u32)v) << 16; return c.f;
}

template <bool BF>
__device__ __forceinline__ float ldg(const void* p, long i) {
  if (BF) return bf2f(((const u16*)p)[i]);
  return ((const float*)p)[i];
}

template <bool BF>
__device__ __forceinline__ f2 ldg2(const void* p, long i) {
  f2 r;
  r.x = ldg<BF>(p, i + 0);
  r.y = ldg<BF>(p, i + 1);
  return r;
}

// Proven rounds 3-17: true-bf16 weights all have |w| <= 1/sqrt(41) ~ 0.156;
// fp32 data read as bf16 halfwords exceeds 0.2 with P ~ 1-1e-10.
__device__ __forceinline__ bool detect_bf16(const void* w) {
  const u16* p = (const u16*)w;
  bool bf = true;
  for (int i = 0; i < 64; ++i) {
    float f = bf2f(p[i]);
    if (!(fabsf(f) <= 0.2f)) bf = false;
  }
  return bf;
}

// Partner value from lane^1 (quad_perm [1,0,3,2]). VALU pipe, no LDS.
__device__ __forceinline__ float pair_other(float x) {
  return __int_as_float(__builtin_amdgcn_update_dpp(
      0, __float_as_int(x), 0xB1, 0xF, 0xF, true));
}

template <bool BF>
__global__ __launch_bounds__(64, 2)
void rnn_kernel(const void* __restrict__ inp,
                const void* __restrict__ h2h_w1, const void* __restrict__ h2h_b1,
                const void* __restrict__ h2h_w2, const void* __restrict__ h2h_b2,
                const void* __restrict__ h2o_w1, const void* __restrict__ h2o_b1,
                const void* __restrict__ h2o_w2, const void* __restrict__ h2o_b2,
                void* __restrict__ out) {
  __shared__ __align__(16) float sH[44];  // hidden state h[0..39]
  __shared__ __align__(16) float sA[84];  // L1 acts: a-rows [0..39], o-rows [40..79]

  if (detect_bf16(h2h_w1) != BF) return;  // wrong-dtype instantiation exits

  const int lane = threadIdx.x & 63;
  const int kh   = lane & 1;          // K-half: 0 -> u + k0..19, 1 -> k20..39
  const int w    = lane >> 1;         // worker 0..31
  const int koff = kh * 20;

  // ---- Slot pointers/offsets (selected ONCE; loads stay remat-friendly) ----
  // slot0/1: L1 rows 2w, 2w+1 (never straddle the 40 boundary)
  const bool hh01 = (2 * w < HID);
  const void* p01 = hh01 ? h2h_w1 : h2o_w1;
  const long  jr0 = hh01 ? 2 * w : 2 * w - HID;   // row pair base
  // slot2: w>=16 -> L1 row 48+w (h2o-L1 row 8+w); w<16 -> L2 row w
  const bool  s2A = (w >= 16);
  const void* p2  = s2A ? h2o_w1 : h2h_w2;
  const long  o2  = s2A ? ((long)(8 + w) * 41 + 1 + koff) : ((long)w * HID + koff);
  // slot3: w<24 -> L2 row 16+w; w==24 -> output row; w>24 idle (garbage)
  const bool  isOut = (w == 24);
  const void* p3  = isOut ? h2o_w2 : h2h_w2;
  const long  o3  = isOut ? (long)koff : ((long)(16 + (w < 24 ? w : 0)) * HID + koff);

  // ---- Load weights (kh-half slices) ----
  f2 s0[10], s1[10], s2[10], s3[10];
#pragma unroll
  for (int i = 0; i < 10; ++i) {
    s0[i] = ldg2<BF>(p01, jr0 * 41 + 1 + koff + 2 * i);
    s1[i] = ldg2<BF>(p01, (jr0 + 1) * 41 + 1 + koff + 2 * i);
    s2[i] = ldg2<BF>(p2, o2 + 2 * i);
    s3[i] = ldg2<BF>(p3, o3 + 2 * i);
  }
  float wu0 = 0.f, wu1 = 0.f, wu2 = 0.f, ba0 = 0.f, ba1 = 0.f, ba2 = 0.f;
  float bb2 = 0.f, bb3 = 0.f;
  if (kh == 0) {
    const void* b1p = hh01 ? h2h_b1 : h2o_b1;
    wu0 = ldg<BF>(p01, jr0 * 41);
    wu1 = ldg<BF>(p01, (jr0 + 1) * 41);
    ba0 = ldg<BF>(b1p, jr0);
    ba1 = ldg<BF>(b1p, jr0 + 1);
    if (s2A) { wu2 = ldg<BF>(h2o_w1, (long)(8 + w) * 41); ba2 = ldg<BF>(h2o_b1, 8 + w); }
    else     { bb2 = ldg<BF>(h2h_b2, w); }
    if (isOut)      bb3 = ldg<BF>(h2o_b2, 0);
    else if (w < 24) bb3 = ldg<BF>(h2h_b2, 16 + w);
  }

  for (int i = lane; i < 44; i += 64) sH[i] = 0.f;
  __syncthreads();

  const long base = (long)blockIdx.x * T_SZ;   // 1 el per block
  float u_cur = ldg<BF>(inp, base);

  const f4* hp = (const f4*)(&sH[koff]);                     // broadcast
  const f4* ap = (const f4*)(&sA[isOut ? 40 + koff : koff]); // broadcast (2 addrs)
  const bool wrA2 = s2A && (kh == 0);
  const bool wr2  = (!s2A) && (kh == 0);        // w<16: new h[w]
  const bool wr3  = (w < 24) && (kh == 0);      // new h[16+w]
  const bool wrY  = isOut && (kh == 0);

  for (int t = 0; t < T_SZ; ++t) {
    const float u_nxt = (t + 1 < T_SZ) ? ldg<BF>(inp, base + t + 1) : 0.f;

    // ---------- Phase A: L1 rows (slots 0,1,2) vs state ----------
    {
      f4 hv4[5];
#pragma unroll
      for (int i = 0; i < 5; ++i) hv4[i] = hp[i];
      const f2* hv = (const f2*)hv4;
      f2 a0 = {0.f, 0.f}, a1 = {0.f, 0.f}, a2 = {0.f, 0.f};
#pragma unroll
      for (int i = 0; i < 10; ++i) {
        a0 = hv[i] * s0[i] + a0;
        a1 = hv[i] * s1[i] + a1;
        a2 = hv[i] * s2[i] + a2;   // garbage for w<16 (not written)
      }
      const float v0 = fmaf(u_cur, wu0, ba0) + a0.x + a0.y;
      const float v1 = fmaf(u_cur, wu1, ba1) + a1.x + a1.y;
      const float v2 = fmaf(u_cur, wu2, ba2) + a2.x + a2.y;
      const float t0 = v0 + pair_other(v0);
      const float t1 = v1 + pair_other(v1);
      const float t2 = v2 + pair_other(v2);
      if (kh == 0) {
        f2 act01;
        act01.x = fmaxf(t0, 0.01f * t0);
        act01.y = fmaxf(t1, 0.01f * t1);
        *(f2*)(&sA[2 * w]) = act01;            // b64, 2-way bank (free)
      }
      if (wrA2) sA[48 + w] = fmaxf(t2, 0.01f * t2);   // o-acts rows 64..79
    }
    __syncthreads();   // single-wave: waitcnt-only ordering

    // ---------- Phase B: L2 rows + output (slots 2,3) vs acts ----------
    {
      f4 av4[5];
#pragma unroll
      for (int i = 0; i < 5; ++i) av4[i] = ap[i];
      const f2* av = (const f2*)av4;
      f2 b2 = {0.f, 0.f}, b3 = {0.f, 0.f};
#pragma unroll
      for (int i = 0; i < 10; ++i) {
        b2 = av[i] * s2[i] + b2;   // garbage for w>=16 (not written)
        b3 = av[i] * s3[i] + b3;   // garbage for w>24 (not written)
      }
      const float v2 = bb2 + b2.x + b2.y;
      const float v3 = bb3 + b3.x + b3.y;
      const float t2 = v2 + pair_other(v2);
      const float t3 = v3 + pair_other(v3);
      if (wr2) sH[w] = t2;                     // new h[0..15]
      if (wr3) sH[16 + w] = t3;                // new h[16..39]
      if (wrY) {                               // y(t)
        if (BF) ((__hip_bfloat16*)out)[base + t] = __float2bfloat16(t3);
        else    ((float*)out)[base + t] = t3;
      }
    }
    __syncthreads();   // acts consumed; safe to overwrite next step

    u_cur = u_nxt;
  }
}

extern "C" void kernel_launch(void* const* d_in, const int* in_sizes, int n_in,
                              void* d_out, int out_size, void* d_ws, size_t ws_size,
                              hipStream_t stream) {
  (void)in_sizes; (void)n_in; (void)out_size; (void)d_ws; (void)ws_size;
  rnn_kernel<false><<<dim3(B_SZ), dim3(64), 0, stream>>>(
      d_in[0], d_in[1], d_in[2], d_in[3], d_in[4],
      d_in[5], d_in[6], d_in[7], d_in[8], d_out);
  rnn_kernel<true><<<dim3(B_SZ), dim3(64), 0, stream>>>(
      d_in[0], d_in[1], d_in[2], d_in[3], d_in[4],
      d_in[5], d_in[6], d_in[7], d_in[8], d_out);
}